// Round 2
// baseline (48407.562 us; speedup 1.0000x reference)
//
#include <hip/hip_runtime.h>
#include <math.h>

#define NPTS 2048
#define KNB 64
#define SPC (KNB*NPTS)   // 131072 spatial positions per conv slab

// ---------- ball query + grouped feature build ----------
// feat layout per cloud: [6][KNB][NPTS]; ch 0..2 = center xyz, 3..5 = rel
__global__ __launch_bounds__(64) void bq_feat(const float* __restrict__ xyz,
                                              float* __restrict__ feat)
{
  const int m = blockIdx.x * 64 + threadIdx.x;
  const float px = xyz[3*m], py = xyz[3*m+1], pz = xyz[3*m+2];
  const float sqm = __fadd_rn(__fadd_rn(__fmul_rn(px,px), __fmul_rn(py,py)), __fmul_rn(pz,pz));
  const float r2 = 0.09f;
  int cnt = 0;
  float fx = 0.f, fy = 0.f, fz = 0.f;
  for (int n = 0; n < NPTS; ++n) {
    const float xn = xyz[3*n], yn = xyz[3*n+1], zn = xyz[3*n+2];
    const float sqn = __fadd_rn(__fadd_rn(__fmul_rn(xn,xn), __fmul_rn(yn,yn)), __fmul_rn(zn,zn));
    const float dt  = __fadd_rn(__fadd_rn(__fmul_rn(px,xn), __fmul_rn(py,yn)), __fmul_rn(pz,zn));
    const float d   = __fsub_rn(__fadd_rn(sqm, sqn), __fmul_rn(2.0f, dt));
    if (d <= r2) {
      const float rx = xn - px, ry = yn - py, rz = zn - pz;
      feat[3*SPC + cnt*NPTS + m] = rx;
      feat[4*SPC + cnt*NPTS + m] = ry;
      feat[5*SPC + cnt*NPTS + m] = rz;
      if (cnt == 0) { fx = rx; fy = ry; fz = rz; }
      if (++cnt == KNB) break;
    }
  }
  for (int k = cnt; k < KNB; ++k) {
    feat[3*SPC + k*NPTS + m] = fx;
    feat[4*SPC + k*NPTS + m] = fy;
    feat[5*SPC + k*NPTS + m] = fz;
  }
  for (int k = 0; k < KNB; ++k) {
    feat[0*SPC + k*NPTS + m] = px;
    feat[1*SPC + k*NPTS + m] = py;
    feat[2*SPC + k*NPTS + m] = pz;
  }
}

// ---------- fused GEMM ----------
// out[o][s] = (sum_c A[o*C+c] * f(B[c*ldb+s]) - (B2? B2[c*ldb+s]:0) ... ) ...
//   f(v) = inStats ? relu((v-mu[c>>5])*rs[c>>5]*inW[c]+inB[c]) : v   (GN groups of 32)
//   then bv -= B2 (raw), accumulate; epilogue: +bias[o], *scaleS[s],
//   optional transposed copy outT[s*O+o], optional atomic {sum,sumsq} per
//   out-channel group of outGrpCh channels into outPart.
// grid (S/64, O/16), block (64,4); each thread computes 4 contiguous o.
__global__ __launch_bounds__(256) void gemm_f(
    const float* __restrict__ A,
    const float* __restrict__ B, long long ldb,
    const float* __restrict__ B2,
    float* __restrict__ out, long long ldo,
    const float* __restrict__ bias,
    const float* __restrict__ scaleS,
    float* __restrict__ outT,
    const float* __restrict__ inStats, const float* __restrict__ inW, const float* __restrict__ inB,
    float* __restrict__ outPart, int outGrpCh,
    int O, int C, int S)
{
  const int s  = blockIdx.x * 64 + threadIdx.x;
  const int o0 = blockIdx.y * 16 + threadIdx.y * 4;
  const float* Ab = A + (long long)o0 * C;
  const float* Bp = B + s;
  const float* B2p = B2 ? B2 + s : nullptr;
  float a0=0.f, a1=0.f, a2=0.f, a3=0.f;
  for (int c = 0; c < C; ++c) {
    float bv = Bp[(long long)c * ldb];
    if (inStats) {
      const int g = c >> 5;
      bv = (bv - inStats[2*g]) * inStats[2*g+1] * inW[c] + inB[c];
      bv = fmaxf(bv, 0.f);
    }
    if (B2p) bv -= B2p[(long long)c * ldb];
    a0 = fmaf(Ab[c],       bv, a0);
    a1 = fmaf(Ab[C + c],   bv, a1);
    a2 = fmaf(Ab[2*C + c], bv, a2);
    a3 = fmaf(Ab[3*C + c], bv, a3);
  }
  const float sc = scaleS ? scaleS[s] : 1.0f;
  float v[4] = {a0, a1, a2, a3};
  float* ob = out + (long long)o0 * ldo + s;
  float ss = 0.f, ss2 = 0.f;
  #pragma unroll
  for (int j = 0; j < 4; ++j) {
    float x = v[j];
    if (bias) x += bias[o0 + j];
    x *= sc;
    ob[(long long)j * ldo] = x;
    if (outT) outT[(long long)s * O + o0 + j] = x;
    ss += x; ss2 = fmaf(x, x, ss2);
  }
  if (outPart) {
    __shared__ float r1[4][64], r2[4][64];
    const int tx = threadIdx.x, ty = threadIdx.y;
    r1[ty][tx] = ss; r2[ty][tx] = ss2;
    __syncthreads();
    for (int st = 32; st; st >>= 1) {
      if (tx < st) { r1[ty][tx] += r1[ty][tx+st]; r2[ty][tx] += r2[ty][tx+st]; }
      __syncthreads();
    }
    if (tx == 0) {
      const int g = o0 / outGrpCh;   // 4-channel span never crosses a group (grp%4==0)
      atomicAdd(&outPart[2*g],   r1[ty][0]);
      atomicAdd(&outPart[2*g+1], r2[ty][0]);
    }
  }
}

// ---------- finalize GN stats: PART {sum,sumsq} -> STATS {mu, rsqrt(var+eps)}; zero PART ----------
__global__ void fin_stats(float* __restrict__ part, float* __restrict__ stats,
                          int G, float invGS)
{
  const int g = threadIdx.x;
  if (g < G) {
    const float mu  = part[2*g] * invGS;
    const float var = part[2*g+1] * invGS - mu*mu;
    stats[2*g]   = mu;
    stats[2*g+1] = rsqrtf(var + 1e-5f);
    part[2*g] = 0.f; part[2*g+1] = 0.f;
  }
}

// ---------- raw max over kc K-rows, accumulate into POOL ----------
__global__ __launch_bounds__(256) void maxpool_racc(const float* __restrict__ c3, int kc,
                                                    float* __restrict__ pool)
{
  const int n = blockIdx.x * 256 + threadIdx.x;
  const int c = blockIdx.y;
  const float* b = c3 + (long long)c * kc * NPTS + n;
  float m = -1e30f;
  for (int r = 0; r < kc; ++r) m = fmaxf(m, b[(long long)r * NPTS]);
  float* p = &pool[c * NPTS + n];
  *p = fmaxf(*p, m);   // sequential chunk launches: safe RMW
}

// ---------- gn+relu in place on pooled [192][NPTS] ----------
__global__ __launch_bounds__(256) void gn_pool(float* __restrict__ pool,
    const float* __restrict__ stats, const float* __restrict__ w, const float* __restrict__ b)
{
  const int i = blockIdx.x * 256 + threadIdx.x;
  const int c = i >> 11;
  const int g = c >> 5;
  const float v = (pool[i] - stats[2*g]) * stats[2*g+1] * w[c] + b[c];
  pool[i] = fmaxf(v, 0.f);
}

// ---------- FEATS slot = xin + relu(gn(t)) ----------
__global__ __launch_bounds__(256) void gn_resid(const float* __restrict__ t,
    const float* __restrict__ xin, const float* __restrict__ stats,
    const float* __restrict__ w, const float* __restrict__ b, float* __restrict__ outp)
{
  const int i = blockIdx.x * 256 + threadIdx.x;
  const int c = i >> 11;
  const int g = c >> 5;
  const float v = (t[i] - stats[2*g]) * stats[2*g+1] * w[c] + b[c];
  outp[i] = xin[i] + fmaxf(v, 0.f);
}

// ---------- row softmax over att[n][:] ----------
__global__ __launch_bounds__(256) void softmax_rows(float* __restrict__ att)
{
  float* a = att + (long long)blockIdx.x * NPTS;
  const int tid = threadIdx.x;
  __shared__ float red[256];
  float mx = -1e30f;
  for (int m = tid; m < NPTS; m += 256) mx = fmaxf(mx, a[m]);
  red[tid] = mx; __syncthreads();
  for (int st = 128; st; st >>= 1) { if (tid < st) red[tid] = fmaxf(red[tid], red[tid+st]); __syncthreads(); }
  mx = red[0]; __syncthreads();
  float sum = 0.f;
  for (int m = tid; m < NPTS; m += 256) { const float e = expf(a[m] - mx); a[m] = e; sum += e; }
  red[tid] = sum; __syncthreads();
  for (int st = 128; st; st >>= 1) { if (tid < st) red[tid] += red[tid+st]; __syncthreads(); }
  const float inv = 1.0f / red[0];
  for (int m = tid; m < NPTS; m += 256) a[m] *= inv;
}

// ---------- column sums of att (over rows n) ----------
__global__ __launch_bounds__(256) void colsum(const float* __restrict__ att, float* __restrict__ s)
{
  const int m = blockIdx.x * 64 + threadIdx.x;
  const int rows = NPTS / gridDim.y;
  const int n0 = blockIdx.y * rows;
  float acc = 0.f;
  for (int n = n0 + threadIdx.y; n < n0 + rows; n += 4)
    acc += att[(long long)n * NPTS + m];
  __shared__ float red[4][64];
  red[threadIdx.y][threadIdx.x] = acc;
  __syncthreads();
  if (threadIdx.y == 0) {
    const float v = red[0][threadIdx.x] + red[1][threadIdx.x] + red[2][threadIdx.x] + red[3][threadIdx.x];
    atomicAdd(&s[m], v);
  }
}

__global__ __launch_bounds__(256) void fill0(float* __restrict__ p, int n)
{ const int i = blockIdx.x*256 + threadIdx.x; if (i < n) p[i] = 0.f; }

__global__ __launch_bounds__(256) void fillv(float* __restrict__ p, int n, float v)
{ const int i = blockIdx.x*256 + threadIdx.x; if (i < n) p[i] = v; }

// 1/(1e-9+s) -> o; zero s for next use
__global__ __launch_bounds__(256) void recip_zero(float* __restrict__ s, float* __restrict__ o, int n)
{ const int i = blockIdx.x*256 + threadIdx.x; if (i < n) { o[i] = 1.0f/(1e-9f + s[i]); s[i] = 0.f; } }

// ---------- fuse epilogue: GN(16 groups of 48) + leaky(0.2) + L2 norm + transpose ----------
__global__ __launch_bounds__(256) void finalize_gn(const float* __restrict__ fused,
    const float* __restrict__ stats, const float* __restrict__ w, const float* __restrict__ b,
    float* __restrict__ outp)
{
  const int n = blockIdx.x, tid = threadIdx.x;
  __shared__ float vbuf[768];
  __shared__ float red[256];
  float ss = 0.f;
  for (int c = tid; c < 768; c += 256) {
    float v = fused[(long long)c * NPTS + n];
    const int g = c / 48;
    v = (v - stats[2*g]) * stats[2*g+1] * w[c] + b[c];
    v = v > 0.f ? v : 0.2f * v;
    vbuf[c] = v;
    ss = fmaf(v, v, ss);
  }
  red[tid] = ss; __syncthreads();
  for (int st = 128; st; st >>= 1) { if (tid < st) red[tid] += red[tid+st]; __syncthreads(); }
  const float inv = 1.0f / (sqrtf(red[0]) + 1e-8f);
  float* ob = outp + (long long)n * 768;
  for (int c = tid; c < 768; c += 256) ob[c] = vbuf[c] * inv;
}

extern "C" void kernel_launch(void* const* d_in, const int* in_sizes, int n_in,
                              void* d_out, int out_size, void* d_ws, size_t ws_size,
                              hipStream_t stream)
{
  const float* src = (const float*)d_in[0];
  const float* tgt = (const float*)d_in[1];
  const float* lfw[3]  = {(const float*)d_in[5], (const float*)d_in[8],  (const float*)d_in[11]};
  const float* lfgw[3] = {(const float*)d_in[6], (const float*)d_in[9],  (const float*)d_in[12]};
  const float* lfgb[3] = {(const float*)d_in[7], (const float*)d_in[10], (const float*)d_in[13]};
  const float* qk_w = (const float*)d_in[14];
  const float* v_w  = (const float*)d_in[15];
  const float* v_b  = (const float*)d_in[16];
  const float* t_w  = (const float*)d_in[17];
  const float* t_b  = (const float*)d_in[18];
  const float* bgw  = (const float*)d_in[19];
  const float* bgb  = (const float*)d_in[20];
  const float* fw   = (const float*)d_in[21];
  const float* fgw  = (const float*)d_in[22];
  const float* fgb  = (const float*)d_in[23];
  float* dout = (float*)d_out;

  // ---- workspace carve-up (floats), adaptive to ws_size ----
  const size_t availFl = ws_size / sizeof(float);
  float* ws = (float*)d_ws;
  size_t off = 0;
  float* POOL  = ws + off; off += (size_t)4*192*NPTS;    // 1,572,864
  float* PART  = ws + off; off += 64*5;                  // 5 slots of {sum,sumsq} pairs
  float* STATS = ws + off; off += 64*5;
  float* SB    = ws + off; off += NPTS;
  float* SINV  = ws + off; off += NPTS;
  off = (off + 255) & ~(size_t)255;
  float* REG = ws + off;
  const size_t regAvail = (availFl > off) ? (availFl - off) : 0;

  // attention-phase view of REG (per-cloud)
  const size_t ATTN_NEED = (size_t)2*48*NPTS + (size_t)3*192*NPTS + (size_t)768*NPTS + (size_t)NPTS*NPTS;
  if (regAvail < ATTN_NEED) return;  // below minimal viable footprint (~35 MB total)

  // conv-phase view: FEAT[6][SPC] + C1[128][Sc] + C2[256][Sc] + C3[192][Sc], Sc = kc*NPTS
  int kc = 0;
  for (int cand = 64; cand >= 1; cand >>= 1)
    if ((size_t)6*SPC + (size_t)576*NPTS*cand <= regAvail) { kc = cand; break; }
  if (!kc) return;
  const int Sc = kc * NPTS;
  const int nChunks = KNB / kc;

  float* FEAT = REG;
  float* C1 = FEAT + (size_t)6*SPC;
  float* C2 = C1 + (size_t)128*Sc;
  float* C3 = C2 + (size_t)256*Sc;

  float* QK  = REG;
  float* QKT = QK  + (size_t)48*NPTS;
  float* V   = QKT + (size_t)48*NPTS;
  float* XR  = V   + (size_t)192*NPTS;
  float* T   = XR  + (size_t)192*NPTS;
  float* FUSED = T + (size_t)192*NPTS;
  float* ATT = FUSED + (size_t)768*NPTS;

  float *P1 = PART,      *S1 = STATS;
  float *P2 = PART + 64, *S2 = STATS + 64;
  float *P3 = PART + 128,*S3 = STATS + 128;
  float *PT = PART + 192,*ST = STATS + 192;
  float *PF = PART + 256,*SF = STATS + 256;

  dim3 b256(256), b64(64), b64x4(64, 4);
  const float invConvGS = 1.0f / (32.0f * (float)SPC);

  // zero PART slots + SB (ws is 0xAA-poisoned each call); fins/recip re-zero after use
  fill0<<<dim3((320 + 255)/256), b256, 0, stream>>>(PART, 320);
  fill0<<<dim3((NPTS + 255)/256), b256, 0, stream>>>(SB, NPTS);

  // ================= conv stage (chunked recompute), per cloud =================
  for (int bb = 0; bb < 4; ++bb) {
    const float* xyz = (bb < 2) ? src + (size_t)bb*NPTS*3 : tgt + (size_t)(bb-2)*NPTS*3;
    float* POOLbb = POOL + (size_t)bb*192*NPTS;
    bq_feat<<<NPTS/64, b64, 0, stream>>>(xyz, FEAT);

    // pass 1: conv1 -> stats1
    for (int ck = 0; ck < nChunks; ++ck)
      gemm_f<<<dim3(Sc/64, 8), b64x4, 0, stream>>>(lfw[0], FEAT + (size_t)ck*Sc, SPC, nullptr,
          C1, Sc, nullptr, nullptr, nullptr, nullptr, nullptr, nullptr, P1, 32, 128, 6, Sc);
    fin_stats<<<1, 16, 0, stream>>>(P1, S1, 4, invConvGS);

    // pass 2: conv1(recompute) -> gn1 -> conv2 -> stats2
    for (int ck = 0; ck < nChunks; ++ck) {
      gemm_f<<<dim3(Sc/64, 8), b64x4, 0, stream>>>(lfw[0], FEAT + (size_t)ck*Sc, SPC, nullptr,
          C1, Sc, nullptr, nullptr, nullptr, nullptr, nullptr, nullptr, nullptr, 0, 128, 6, Sc);
      gemm_f<<<dim3(Sc/64, 16), b64x4, 0, stream>>>(lfw[1], C1, Sc, nullptr,
          C2, Sc, nullptr, nullptr, nullptr, S1, lfgw[0], lfgb[0], P2, 32, 256, 128, Sc);
    }
    fin_stats<<<1, 16, 0, stream>>>(P2, S2, 8, invConvGS);

    // pass 3: conv1 -> gn1 -> conv2 -> gn2 -> conv3 -> stats3 + raw maxpool
    fillv<<<dim3((192*NPTS)/256), b256, 0, stream>>>(POOLbb, 192*NPTS, -1e30f);
    for (int ck = 0; ck < nChunks; ++ck) {
      gemm_f<<<dim3(Sc/64, 8), b64x4, 0, stream>>>(lfw[0], FEAT + (size_t)ck*Sc, SPC, nullptr,
          C1, Sc, nullptr, nullptr, nullptr, nullptr, nullptr, nullptr, nullptr, 0, 128, 6, Sc);
      gemm_f<<<dim3(Sc/64, 16), b64x4, 0, stream>>>(lfw[1], C1, Sc, nullptr,
          C2, Sc, nullptr, nullptr, nullptr, S1, lfgw[0], lfgb[0], nullptr, 0, 256, 128, Sc);
      gemm_f<<<dim3(Sc/64, 12), b64x4, 0, stream>>>(lfw[2], C2, Sc, nullptr,
          C3, Sc, nullptr, nullptr, nullptr, S2, lfgw[1], lfgb[1], P3, 32, 192, 256, Sc);
      maxpool_racc<<<dim3(NPTS/256, 192), b256, 0, stream>>>(C3, kc, POOLbb);
    }
    fin_stats<<<1, 16, 0, stream>>>(P3, S3, 6, invConvGS);
    // gn monotone per channel (gnw==1>0) => max commutes; apply gn3+relu on pooled map
    gn_pool<<<dim3((192*NPTS)/256), b256, 0, stream>>>(POOLbb, S3, lfgw[2], lfgb[2]);
  }

  // ================= attention + fuse, per cloud =================
  for (int bb = 0; bb < 4; ++bb) {
    float* FEATSbb = dout + (size_t)bb*768*NPTS;   // FEATS lives in d_out
    const float* Xin = POOL + (size_t)bb*192*NPTS;
    for (int i = 0; i < 4; ++i) {
      const float* qwi = qk_w + (size_t)i*48*192;
      const float* vwi = v_w  + (size_t)i*192*192;
      const float* twi = t_w  + (size_t)i*192*192;
      gemm_f<<<dim3(NPTS/64, 3), b64x4, 0, stream>>>(qwi, Xin, NPTS, nullptr,
          QK, NPTS, nullptr, nullptr, QKT, nullptr, nullptr, nullptr, nullptr, 0, 48, 192, NPTS);
      gemm_f<<<dim3(NPTS/64, 12), b64x4, 0, stream>>>(vwi, Xin, NPTS, nullptr,
          V, NPTS, v_b + (size_t)i*192, nullptr, nullptr, nullptr, nullptr, nullptr, nullptr, 0, 192, 192, NPTS);
      gemm_f<<<dim3(NPTS/64, 128), b64x4, 0, stream>>>(QKT, QK, NPTS, nullptr,
          ATT, NPTS, nullptr, nullptr, nullptr, nullptr, nullptr, nullptr, nullptr, 0, NPTS, 48, NPTS);
      softmax_rows<<<NPTS, b256, 0, stream>>>(ATT);
      colsum<<<dim3(NPTS/64, 8), b64x4, 0, stream>>>(ATT, SB);
      recip_zero<<<dim3(NPTS/256), b256, 0, stream>>>(SB, SINV, NPTS);
      gemm_f<<<dim3(NPTS/64, 12), b64x4, 0, stream>>>(V, ATT, NPTS, nullptr,
          XR, NPTS, nullptr, SINV, nullptr, nullptr, nullptr, nullptr, nullptr, 0, 192, NPTS, NPTS);
      gemm_f<<<dim3(NPTS/64, 12), b64x4, 0, stream>>>(twi, Xin, NPTS, XR,
          T, NPTS, t_b + (size_t)i*192, nullptr, nullptr, nullptr, nullptr, nullptr, PT, 32, 192, 192, NPTS);
      fin_stats<<<1, 16, 0, stream>>>(PT, ST, 6, 1.0f/65536.0f);
      float* slot = FEATSbb + (size_t)i*192*NPTS;
      gn_resid<<<dim3((192*NPTS)/256), b256, 0, stream>>>(T, Xin, ST,
          bgw + (size_t)i*192, bgb + (size_t)i*192, slot);
      Xin = slot;
    }
    // fuse: 768x768 @ FEATS(=d_out region) -> FUSED(ws); stats for GN16
    gemm_f<<<dim3(NPTS/64, 48), b64x4, 0, stream>>>(fw, FEATSbb, NPTS, nullptr,
        FUSED, NPTS, nullptr, nullptr, nullptr, nullptr, nullptr, nullptr, PF, 48, 768, 768, NPTS);
    fin_stats<<<1, 16, 0, stream>>>(PF, SF, 16, 1.0f/98304.0f);
    // GN + leaky + transpose + L2 normalize, overwriting this cloud's d_out region
    finalize_gn<<<NPTS, b256, 0, stream>>>(FUSED, SF, fgw, fgb, FEATSbb);
  }
}

// Round 3
// 5736.039 us; speedup vs baseline: 8.4392x; 8.4392x over previous
//
#include <hip/hip_runtime.h>
#include <math.h>

#define NPTS 2048
#define KNB 64
#define SPC (KNB*NPTS)   // 131072 spatial positions per conv slab

// ---------- ball query + grouped feature build ----------
__global__ __launch_bounds__(64) void bq_feat(const float* __restrict__ xyz,
                                              float* __restrict__ feat)
{
  const int m = blockIdx.x * 64 + threadIdx.x;
  const float px = xyz[3*m], py = xyz[3*m+1], pz = xyz[3*m+2];
  const float sqm = __fadd_rn(__fadd_rn(__fmul_rn(px,px), __fmul_rn(py,py)), __fmul_rn(pz,pz));
  const float r2 = 0.09f;
  int cnt = 0;
  float fx = 0.f, fy = 0.f, fz = 0.f;
  for (int n = 0; n < NPTS; ++n) {
    const float xn = xyz[3*n], yn = xyz[3*n+1], zn = xyz[3*n+2];
    const float sqn = __fadd_rn(__fadd_rn(__fmul_rn(xn,xn), __fmul_rn(yn,yn)), __fmul_rn(zn,zn));
    const float dt  = __fadd_rn(__fadd_rn(__fmul_rn(px,xn), __fmul_rn(py,yn)), __fmul_rn(pz,zn));
    const float d   = __fsub_rn(__fadd_rn(sqm, sqn), __fmul_rn(2.0f, dt));
    if (d <= r2) {
      const float rx = xn - px, ry = yn - py, rz = zn - pz;
      feat[3*SPC + cnt*NPTS + m] = rx;
      feat[4*SPC + cnt*NPTS + m] = ry;
      feat[5*SPC + cnt*NPTS + m] = rz;
      if (cnt == 0) { fx = rx; fy = ry; fz = rz; }
      if (++cnt == KNB) break;
    }
  }
  for (int k = cnt; k < KNB; ++k) {
    feat[3*SPC + k*NPTS + m] = fx;
    feat[4*SPC + k*NPTS + m] = fy;
    feat[5*SPC + k*NPTS + m] = fz;
  }
  for (int k = 0; k < KNB; ++k) {
    feat[0*SPC + k*NPTS + m] = px;
    feat[1*SPC + k*NPTS + m] = py;
    feat[2*SPC + k*NPTS + m] = pz;
  }
}

// ---------- tiled fused GEMM ----------
// out[z][o][s] = ( sum_c A[z][o][c] * f(B[z][c][s]) ) (+bias[o]) * scaleS[z][s]
//   f(v) = inStats ? relu((v-mu[c/32])*rs[c/32]*inW[c]+inB[c]) : v, then -= B2[z][c][s]
// optional outT[z][s][o]; optional per-group {sum,sumsq} atomics into outPart
// (block-level LDS reduction first). Tile BSxBO, 256 threads, TSxTO per thread.
template<int BS, int BO, int TS, int TO>
__global__ __launch_bounds__(256) void gemm_t(
    const float* __restrict__ A, long long aZ,
    const float* __restrict__ B, long long ldb, long long bZ,
    const float* __restrict__ B2, long long b2Z,
    float* __restrict__ out, long long ldo, long long oZ,
    const float* __restrict__ bias,
    const float* __restrict__ scaleS, long long sZ,
    float* __restrict__ outT, long long tZ,
    const float* __restrict__ inStats,
    const float* __restrict__ inW, const float* __restrict__ inB,
    float* __restrict__ outPart, long long pZ, int grpCh,
    int O, int C, int S)
{
  constexpr int BC = 16;
  constexpr int NTX = BS / TS;
  constexpr int NTY = BO / TO;
  static_assert(NTX * NTY == 256, "bad tile");
  __shared__ float As[BC][BO];   // [c][o]
  __shared__ float Bs[BC][BS];   // [c][s]
  __shared__ float gS[8], gQ[8];

  const int tid = threadIdx.x;
  const int tx = tid % NTX, ty = tid / NTX;
  const int z = blockIdx.z;
  const int s_blk = blockIdx.x * BS;
  const int o_blk = blockIdx.y * BO;

  const float* Az  = A + (long long)z * aZ;
  const float* Bz  = B + (long long)z * bZ;
  const float* B2z = B2 ? B2 + (long long)z * b2Z : nullptr;

  float acc[TO][TS];
  #pragma unroll
  for (int i = 0; i < TO; ++i)
    #pragma unroll
    for (int j = 0; j < TS; ++j) acc[i][j] = 0.f;

  const int aq = tid % (BC/4), ar = tid / (BC/4);
  const int bq = tid % (BS/4), br = tid / (BS/4);
  const bool cAligned = ((C & 3) == 0);

  for (int c0 = 0; c0 < C; c0 += BC) {
    __syncthreads();
    // stage A tile (transpose to [c][o])
    for (int ol = ar; ol < BO; ol += 256/(BC/4)) {
      const int o = o_blk + ol;
      const int c = c0 + aq*4;
      float v0=0.f, v1=0.f, v2=0.f, v3=0.f;
      if (o < O) {
        if (cAligned && c + 3 < C) {
          const float4 v = *(const float4*)&Az[(long long)o*C + c];
          v0 = v.x; v1 = v.y; v2 = v.z; v3 = v.w;
        } else {
          if (c   < C) v0 = Az[(long long)o*C + c];
          if (c+1 < C) v1 = Az[(long long)o*C + c+1];
          if (c+2 < C) v2 = Az[(long long)o*C + c+2];
          if (c+3 < C) v3 = Az[(long long)o*C + c+3];
        }
      }
      As[aq*4+0][ol] = v0; As[aq*4+1][ol] = v1;
      As[aq*4+2][ol] = v2; As[aq*4+3][ol] = v3;
    }
    // stage B tile (with fused input transform)
    for (int cl = br; cl < BC; cl += 256/(BS/4)) {
      const int c = c0 + cl;
      float4 v = make_float4(0.f, 0.f, 0.f, 0.f);
      if (c < C) {
        const long long boff = (long long)c*ldb + s_blk + bq*4;
        v = *(const float4*)&Bz[boff];
        if (inStats) {
          const int g = c >> 5;
          const float mu = inStats[2*g], rs = inStats[2*g+1];
          const float w = inW[c], b_ = inB[c];
          v.x = fmaxf((v.x-mu)*rs*w + b_, 0.f);
          v.y = fmaxf((v.y-mu)*rs*w + b_, 0.f);
          v.z = fmaxf((v.z-mu)*rs*w + b_, 0.f);
          v.w = fmaxf((v.w-mu)*rs*w + b_, 0.f);
        }
        if (B2z) {
          const float4 u = *(const float4*)&B2z[boff];
          v.x -= u.x; v.y -= u.y; v.z -= u.z; v.w -= u.w;
        }
      }
      *(float4*)&Bs[cl][bq*4] = v;
    }
    __syncthreads();
    // compute
    #pragma unroll
    for (int k = 0; k < BC; ++k) {
      float a[TO], b[TS];
      *(float4*)&b[0] = *(const float4*)&Bs[k][tx*TS];
      if constexpr (TS == 8) *(float4*)&b[4] = *(const float4*)&Bs[k][tx*TS + 4];
      *(float4*)&a[0] = *(const float4*)&As[k][ty*TO];
      if constexpr (TO == 8) *(float4*)&a[4] = *(const float4*)&As[k][ty*TO + 4];
      #pragma unroll
      for (int oo = 0; oo < TO; ++oo)
        #pragma unroll
        for (int ss = 0; ss < TS; ++ss)
          acc[oo][ss] = fmaf(a[oo], b[ss], acc[oo][ss]);
    }
  }

  // epilogue
  const int s0 = s_blk + tx*TS;
  float scv[TS];
  #pragma unroll
  for (int ss = 0; ss < TS; ++ss)
    scv[ss] = scaleS ? scaleS[(long long)z*sZ + s0 + ss] : 1.0f;
  float* oz = out + (long long)z * oZ;
  float rsum[TO], rsq[TO];
  #pragma unroll
  for (int oo = 0; oo < TO; ++oo) { rsum[oo] = 0.f; rsq[oo] = 0.f; }
  #pragma unroll
  for (int oo = 0; oo < TO; ++oo) {
    const int o = o_blk + ty*TO + oo;
    if (o < O) {
      float vr[TS];
      const float bv = bias ? bias[o] : 0.f;
      float rs_ = 0.f, rq_ = 0.f;
      #pragma unroll
      for (int ss = 0; ss < TS; ++ss) {
        float v = (acc[oo][ss] + bv) * scv[ss];
        vr[ss] = v; rs_ += v; rq_ = fmaf(v, v, rq_);
      }
      rsum[oo] = rs_; rsq[oo] = rq_;
      *(float4*)&oz[(long long)o*ldo + s0] = make_float4(vr[0], vr[1], vr[2], vr[3]);
      if constexpr (TS == 8)
        *(float4*)&oz[(long long)o*ldo + s0 + 4] = make_float4(vr[4], vr[5], vr[6], vr[7]);
      if (outT) {
        float* tz = outT + (long long)z * tZ;
        #pragma unroll
        for (int ss = 0; ss < TS; ++ss) tz[(long long)(s0+ss)*O + o] = vr[ss];
      }
    }
  }
  if (outPart) {
    __syncthreads();                 // LDS reuse for row sums
    float* rowS = &As[0][0];
    float* rowQ = &Bs[0][0];
    #pragma unroll
    for (int oo = 0; oo < TO; ++oo) {
      float rs_ = rsum[oo], rq_ = rsq[oo];
      for (int d = NTX/2; d; d >>= 1) {
        rs_ += __shfl_down(rs_, d, NTX);
        rq_ += __shfl_down(rq_, d, NTX);
      }
      if (tx == 0) { rowS[ty*TO + oo] = rs_; rowQ[ty*TO + oo] = rq_; }
    }
    if (tid < 8) { gS[tid] = 0.f; gQ[tid] = 0.f; }
    __syncthreads();
    const int g0 = o_blk / grpCh;
    if (tid < BO && (o_blk + tid) < O) {
      const int gl = (o_blk + tid) / grpCh - g0;
      atomicAdd(&gS[gl], rowS[tid]);
      atomicAdd(&gQ[gl], rowQ[tid]);
    }
    __syncthreads();
    const int oTop = ((o_blk + BO < O) ? (o_blk + BO) : O) - 1;
    const int maxgl = oTop / grpCh - g0;
    if (tid <= maxgl) {
      float* pz = outPart + (long long)z * pZ;
      atomicAdd(&pz[2*(g0 + tid)],     gS[tid]);
      atomicAdd(&pz[2*(g0 + tid) + 1], gQ[tid]);
    }
  }
}

// ---------- finalize GN stats: {sum,sumsq} -> {mu, rsqrt(var+eps)}; zero part ----------
__global__ void fin_stats(float* __restrict__ part, float* __restrict__ stats,
                          long long slotStride, int G, float invGS)
{
  const int g = threadIdx.x;
  float* p  = part  + (long long)blockIdx.x * slotStride;
  float* st = stats + (long long)blockIdx.x * slotStride;
  if (g < G) {
    const float mu  = p[2*g] * invGS;
    const float var = p[2*g+1] * invGS - mu*mu;
    st[2*g]   = mu;
    st[2*g+1] = rsqrtf(var + 1e-5f);
    p[2*g] = 0.f; p[2*g+1] = 0.f;
  }
}

// ---------- raw max over kc K-rows, accumulate into POOL ----------
__global__ __launch_bounds__(256) void maxpool_racc(const float* __restrict__ c3, int kc,
                                                    float* __restrict__ pool)
{
  const int n = blockIdx.x * 256 + threadIdx.x;
  const int c = blockIdx.y;
  const float* b = c3 + (long long)c * kc * NPTS + n;
  float m = -1e30f;
  for (int r = 0; r < kc; ++r) m = fmaxf(m, b[(long long)r * NPTS]);
  float* p = &pool[c * NPTS + n];
  *p = fmaxf(*p, m);
}

// ---------- gn+relu in place on pooled [192][NPTS] ----------
__global__ __launch_bounds__(256) void gn_pool(float* __restrict__ pool,
    const float* __restrict__ stats, const float* __restrict__ w, const float* __restrict__ b)
{
  const int i = blockIdx.x * 256 + threadIdx.x;
  const int c = i >> 11;
  const int g = c >> 5;
  const float v = (pool[i] - stats[2*g]) * stats[2*g+1] * w[c] + b[c];
  pool[i] = fmaxf(v, 0.f);
}

// ---------- FEATS slot = xin + relu(gn(t)), z-batched ----------
__global__ __launch_bounds__(256) void gn_resid(const float* __restrict__ t, long long tZ,
    const float* __restrict__ xin, long long xZ,
    const float* __restrict__ stats, long long stZ,
    const float* __restrict__ w, const float* __restrict__ b,
    float* __restrict__ outp, long long oZ)
{
  const int i = blockIdx.x * 256 + threadIdx.x;
  const int z = blockIdx.y;
  const int c = i >> 11;
  const int g = c >> 5;
  const float* st = stats + (long long)z * stZ;
  const float v = (t[(long long)z*tZ + i] - st[2*g]) * st[2*g+1] * w[c] + b[c];
  outp[(long long)z*oZ + i] = xin[(long long)z*xZ + i] + fmaxf(v, 0.f);
}

// ---------- row softmax, z-batched ----------
__global__ __launch_bounds__(256) void softmax_rows(float* __restrict__ att)
{
  float* a = att + (long long)blockIdx.y * NPTS * NPTS + (long long)blockIdx.x * NPTS;
  const int tid = threadIdx.x;
  __shared__ float red[256];
  float mx = -1e30f;
  for (int m = tid; m < NPTS; m += 256) mx = fmaxf(mx, a[m]);
  red[tid] = mx; __syncthreads();
  for (int st = 128; st; st >>= 1) { if (tid < st) red[tid] = fmaxf(red[tid], red[tid+st]); __syncthreads(); }
  mx = red[0]; __syncthreads();
  float sum = 0.f;
  for (int m = tid; m < NPTS; m += 256) { const float e = expf(a[m] - mx); a[m] = e; sum += e; }
  red[tid] = sum; __syncthreads();
  for (int st = 128; st; st >>= 1) { if (tid < st) red[tid] += red[tid+st]; __syncthreads(); }
  const float inv = 1.0f / red[0];
  for (int m = tid; m < NPTS; m += 256) a[m] *= inv;
}

// ---------- column sums of att, z-batched ----------
__global__ __launch_bounds__(256) void colsum(const float* __restrict__ att, float* __restrict__ s)
{
  const int m = blockIdx.x * 64 + threadIdx.x;
  const int z = blockIdx.z;
  const float* az = att + (long long)z * NPTS * NPTS;
  const int rows = NPTS / gridDim.y;
  const int n0 = blockIdx.y * rows;
  float acc = 0.f;
  for (int n = n0 + threadIdx.y; n < n0 + rows; n += 4)
    acc += az[(long long)n * NPTS + m];
  __shared__ float red[4][64];
  red[threadIdx.y][threadIdx.x] = acc;
  __syncthreads();
  if (threadIdx.y == 0) {
    const float v = red[0][threadIdx.x] + red[1][threadIdx.x] + red[2][threadIdx.x] + red[3][threadIdx.x];
    atomicAdd(&s[z*NPTS + m], v);
  }
}

__global__ __launch_bounds__(256) void fill0(float* __restrict__ p, int n)
{ const int i = blockIdx.x*256 + threadIdx.x; if (i < n) p[i] = 0.f; }

__global__ __launch_bounds__(256) void fillv(float* __restrict__ p, int n, float v)
{ const int i = blockIdx.x*256 + threadIdx.x; if (i < n) p[i] = v; }

__global__ __launch_bounds__(256) void recip_zero(float* __restrict__ s, float* __restrict__ o, int n)
{ const int i = blockIdx.x*256 + threadIdx.x; if (i < n) { o[i] = 1.0f/(1e-9f + s[i]); s[i] = 0.f; } }

// ---------- fuse epilogue: GN(groups of 48) + leaky(0.2) + L2 norm + transpose, z-batched ----------
__global__ __launch_bounds__(256) void finalize_gn(const float* __restrict__ fused, long long fZ,
    const float* __restrict__ stats, long long stZ,
    const float* __restrict__ w, const float* __restrict__ b,
    float* __restrict__ outp, long long oZ)
{
  const int n = blockIdx.x, z = blockIdx.y, tid = threadIdx.x;
  const float* fz = fused + (long long)z * fZ;
  const float* st = stats + (long long)z * stZ;
  __shared__ float vbuf[768];
  __shared__ float red[256];
  float ss = 0.f;
  for (int c = tid; c < 768; c += 256) {
    float v = fz[(long long)c * NPTS + n];
    const int g = c / 48;
    v = (v - st[2*g]) * st[2*g+1] * w[c] + b[c];
    v = v > 0.f ? v : 0.2f * v;
    vbuf[c] = v;
    ss = fmaf(v, v, ss);
  }
  red[tid] = ss; __syncthreads();
  for (int st_ = 128; st_; st_ >>= 1) { if (tid < st_) red[tid] += red[tid+st_]; __syncthreads(); }
  const float inv = 1.0f / (sqrtf(red[0]) + 1e-8f);
  float* ob = outp + (long long)z * oZ + (long long)n * 768;
  for (int c = tid; c < 768; c += 256) ob[c] = vbuf[c] * inv;
}

extern "C" void kernel_launch(void* const* d_in, const int* in_sizes, int n_in,
                              void* d_out, int out_size, void* d_ws, size_t ws_size,
                              hipStream_t stream)
{
  const float* src = (const float*)d_in[0];
  const float* tgt = (const float*)d_in[1];
  const float* lfw[3]  = {(const float*)d_in[5], (const float*)d_in[8],  (const float*)d_in[11]};
  const float* lfgw[3] = {(const float*)d_in[6], (const float*)d_in[9],  (const float*)d_in[12]};
  const float* lfgb[3] = {(const float*)d_in[7], (const float*)d_in[10], (const float*)d_in[13]};
  const float* qk_w = (const float*)d_in[14];
  const float* v_w  = (const float*)d_in[15];
  const float* v_b  = (const float*)d_in[16];
  const float* t_w  = (const float*)d_in[17];
  const float* t_b  = (const float*)d_in[18];
  const float* bgw  = (const float*)d_in[19];
  const float* bgb  = (const float*)d_in[20];
  const float* fw   = (const float*)d_in[21];
  const float* fgw  = (const float*)d_in[22];
  const float* fgb  = (const float*)d_in[23];
  float* dout = (float*)d_out;

  const size_t availFl = ws_size / sizeof(float);
  float* ws = (float*)d_ws;
  size_t off = 0;
  float* POOL  = ws + off; off += (size_t)4*192*NPTS;
  float* PART  = ws + off; off += 512;
  float* STATS = ws + off; off += 512;
  float* SB    = ws + off; off += (size_t)4*NPTS;
  float* SINV  = ws + off; off += (size_t)4*NPTS;
  off = (off + 255) & ~(size_t)255;
  float* REG = ws + off;
  const size_t regAvail = (availFl > off) ? (availFl - off) : 0;

  // attention z-batching factor
  const size_t perZ = (size_t)NPTS*NPTS + (size_t)1440*NPTS;
  int nz;
  if      (regAvail >= 4*perZ) nz = 4;
  else if (regAvail >= 2*perZ) nz = 2;
  else if (regAvail >= perZ)   nz = 1;
  else return;

  // conv chunking
  int kc = 0;
  for (int cand = 64; cand >= 1; cand >>= 1)
    if ((size_t)6*SPC + (size_t)576*NPTS*cand <= regAvail) { kc = cand; break; }
  if (!kc) return;
  const int Sc = kc * NPTS;
  const int nChunks = KNB / kc;

  float* FEAT = REG;
  float* C1 = FEAT + (size_t)6*SPC;
  float* C2 = C1 + (size_t)128*Sc;
  float* C3 = C2 + (size_t)256*Sc;

  float* ATT   = REG;
  float* QK    = ATT  + (size_t)nz*NPTS*NPTS;
  float* QKT   = QK   + (size_t)nz*48*NPTS;
  float* V     = QKT  + (size_t)nz*48*NPTS;
  float* XR    = V    + (size_t)nz*192*NPTS;
  float* T     = XR   + (size_t)nz*192*NPTS;
  float* FUSED = T    + (size_t)nz*192*NPTS;

  dim3 b256(256), b64(64), b64x4(64, 4);
  const float invConvGS = 1.0f / (32.0f * (float)SPC);

  fill0<<<dim3(2), b256, 0, stream>>>(PART, 512);
  fill0<<<dim3(32), b256, 0, stream>>>(SB, 4*NPTS);

  // ================= conv stage (chunked recompute), per cloud =================
  for (int bb = 0; bb < 4; ++bb) {
    const float* xyz = (bb < 2) ? src + (size_t)bb*NPTS*3 : tgt + (size_t)(bb-2)*NPTS*3;
    float* POOLbb = POOL + (size_t)bb*192*NPTS;
    bq_feat<<<NPTS/64, b64, 0, stream>>>(xyz, FEAT);

    // pass 1: conv1 -> stats1
    for (int ck = 0; ck < nChunks; ++ck)
      gemm_t<128,128,8,8><<<dim3(Sc/128, 1, 1), b256, 0, stream>>>(
          lfw[0],0, FEAT+(size_t)ck*Sc,SPC,0, nullptr,0, C1,Sc,0,
          nullptr, nullptr,0, nullptr,0, nullptr,nullptr,nullptr,
          PART,0,32, 128,6,Sc);
    fin_stats<<<1, 32, 0, stream>>>(PART, STATS, 0, 4, invConvGS);

    // pass 2: conv1 -> gn1 -> conv2 -> stats2
    for (int ck = 0; ck < nChunks; ++ck) {
      gemm_t<128,128,8,8><<<dim3(Sc/128, 1, 1), b256, 0, stream>>>(
          lfw[0],0, FEAT+(size_t)ck*Sc,SPC,0, nullptr,0, C1,Sc,0,
          nullptr, nullptr,0, nullptr,0, nullptr,nullptr,nullptr,
          nullptr,0,1, 128,6,Sc);
      gemm_t<128,128,8,8><<<dim3(Sc/128, 2, 1), b256, 0, stream>>>(
          lfw[1],0, C1,Sc,0, nullptr,0, C2,Sc,0,
          nullptr, nullptr,0, nullptr,0, STATS,lfgw[0],lfgb[0],
          PART+64,0,32, 256,128,Sc);
    }
    fin_stats<<<1, 32, 0, stream>>>(PART+64, STATS+64, 0, 8, invConvGS);

    // pass 3: conv1 -> gn1 -> conv2 -> gn2 -> conv3 -> stats3 + raw maxpool
    fillv<<<dim3(192*NPTS/256), b256, 0, stream>>>(POOLbb, 192*NPTS, -1e30f);
    for (int ck = 0; ck < nChunks; ++ck) {
      gemm_t<128,128,8,8><<<dim3(Sc/128, 1, 1), b256, 0, stream>>>(
          lfw[0],0, FEAT+(size_t)ck*Sc,SPC,0, nullptr,0, C1,Sc,0,
          nullptr, nullptr,0, nullptr,0, nullptr,nullptr,nullptr,
          nullptr,0,1, 128,6,Sc);
      gemm_t<128,128,8,8><<<dim3(Sc/128, 2, 1), b256, 0, stream>>>(
          lfw[1],0, C1,Sc,0, nullptr,0, C2,Sc,0,
          nullptr, nullptr,0, nullptr,0, STATS,lfgw[0],lfgb[0],
          nullptr,0,1, 256,128,Sc);
      gemm_t<128,128,8,8><<<dim3(Sc/128, 2, 1), b256, 0, stream>>>(
          lfw[2],0, C2,Sc,0, nullptr,0, C3,Sc,0,
          nullptr, nullptr,0, nullptr,0, STATS+64,lfgw[1],lfgb[1],
          PART+128,0,32, 192,256,Sc);
      maxpool_racc<<<dim3(NPTS/256, 192), b256, 0, stream>>>(C3, kc, POOLbb);
    }
    fin_stats<<<1, 32, 0, stream>>>(PART+128, STATS+128, 0, 6, invConvGS);
    gn_pool<<<dim3(192*NPTS/256), b256, 0, stream>>>(POOLbb, STATS+128, lfgw[2], lfgb[2]);
  }

  // ================= attention + fuse, nz clouds per batch =================
  for (int bb0 = 0; bb0 < 4; bb0 += nz) {
    for (int i = 0; i < 4; ++i) {
      const float* Xb; long long xZ;
      if (i == 0) { Xb = POOL + (size_t)bb0*192*NPTS; xZ = 192LL*NPTS; }
      else        { Xb = dout + (size_t)bb0*768*NPTS + (size_t)(i-1)*192*NPTS; xZ = 768LL*NPTS; }
      // qk (+ transposed copy)
      gemm_t<64,64,4,4><<<dim3(NPTS/64, 1, nz), b256, 0, stream>>>(
          qk_w+(size_t)i*48*192,0, Xb,NPTS,xZ, nullptr,0,
          QK,NPTS,48LL*NPTS, nullptr, nullptr,0, QKT,48LL*NPTS,
          nullptr,nullptr,nullptr, nullptr,0,1, 48,192,NPTS);
      // v
      gemm_t<64,64,4,4><<<dim3(NPTS/64, 3, nz), b256, 0, stream>>>(
          v_w+(size_t)i*192*192,0, Xb,NPTS,xZ, nullptr,0,
          V,NPTS,192LL*NPTS, v_b+(size_t)i*192, nullptr,0, nullptr,0,
          nullptr,nullptr,nullptr, nullptr,0,1, 192,192,NPTS);
      // att = QKT @ QK
      gemm_t<128,128,8,8><<<dim3(NPTS/128, NPTS/128, nz), b256, 0, stream>>>(
          QKT,48LL*NPTS, QK,NPTS,48LL*NPTS, nullptr,0,
          ATT,NPTS,(long long)NPTS*NPTS, nullptr, nullptr,0, nullptr,0,
          nullptr,nullptr,nullptr, nullptr,0,1, NPTS,48,NPTS);
      softmax_rows<<<dim3(NPTS, nz), b256, 0, stream>>>(ATT);
      colsum<<<dim3(NPTS/64, 8, nz), b64x4, 0, stream>>>(ATT, SB);
      recip_zero<<<dim3(nz*NPTS/256), b256, 0, stream>>>(SB, SINV, nz*NPTS);
      // x_r = (V @ att) * sinv
      gemm_t<64,64,4,4><<<dim3(NPTS/64, 3, nz), b256, 0, stream>>>(
          V,192LL*NPTS, ATT,NPTS,(long long)NPTS*NPTS, nullptr,0,
          XR,NPTS,192LL*NPTS, nullptr, SINV,NPTS, nullptr,0,
          nullptr,nullptr,nullptr, nullptr,0,1, 192,NPTS,NPTS);
      // t = t_w @ (x - x_r) + t_b, + group stats
      gemm_t<64,64,4,4><<<dim3(NPTS/64, 3, nz), b256, 0, stream>>>(
          t_w+(size_t)i*192*192,0, Xb,NPTS,xZ, XR,192LL*NPTS,
          T,NPTS,192LL*NPTS, t_b+(size_t)i*192, nullptr,0, nullptr,0,
          nullptr,nullptr,nullptr, PART+192,16,32, 192,192,NPTS);
      fin_stats<<<nz, 32, 0, stream>>>(PART+192, STATS+192, 16, 6, 1.0f/65536.0f);
      gn_resid<<<dim3(192*NPTS/256, nz), b256, 0, stream>>>(
          T,192LL*NPTS, Xb,xZ, STATS+192,16,
          bgw+(size_t)i*192, bgb+(size_t)i*192,
          dout+(size_t)bb0*768*NPTS+(size_t)i*192*NPTS, 768LL*NPTS);
    }
    // fuse
    gemm_t<128,128,8,8><<<dim3(NPTS/128, 6, nz), b256, 0, stream>>>(
        fw,0, dout+(size_t)bb0*768*NPTS,NPTS,768LL*NPTS, nullptr,0,
        FUSED,NPTS,768LL*NPTS, nullptr, nullptr,0, nullptr,0,
        nullptr,nullptr,nullptr, PART+320,32,48, 768,768,NPTS);
    fin_stats<<<nz, 32, 0, stream>>>(PART+320, STATS+320, 32, 16, 1.0f/98304.0f);
    finalize_gn<<<dim3(NPTS, nz), b256, 0, stream>>>(
        FUSED,768LL*NPTS, STATS+320,32, fgw, fgb,
        dout+(size_t)bb0*768*NPTS, 768LL*NPTS);
  }
}

// Round 4
// 2054.323 us; speedup vs baseline: 23.5638x; 2.7922x over previous
//
#include <hip/hip_runtime.h>
#include <hip/hip_bf16.h>
#include <math.h>

#define NPTS 2048
#define KNB 64
#define SPC (KNB*NPTS)

typedef short bf16x8 __attribute__((ext_vector_type(8)));
typedef float f32x4 __attribute__((ext_vector_type(4)));

static __device__ inline short f2b(float f){ __hip_bfloat16 h = __float2bfloat16(f); short s; __builtin_memcpy(&s,&h,2); return s; }
static __device__ inline float b2f(short s){ __hip_bfloat16 h; __builtin_memcpy(&h,&s,2); return __bfloat162float(h); }

// ---------- weight convert fp32[O][Cs] -> bf16[O][Cd] (zero pad c>=Cs) ----------
__global__ __launch_bounds__(256) void cvt_w(const float* __restrict__ src, short* __restrict__ dst,
                                             int O, int Cs, int Cd)
{
  const int i = blockIdx.x*256 + threadIdx.x;
  if (i >= O*Cd) return;
  const int o = i / Cd, c = i % Cd;
  dst[i] = (c < Cs) ? f2b(src[o*Cs + c]) : (short)0;
}

__global__ __launch_bounds__(256) void fill0(float* __restrict__ p, int n)
{ const int i = blockIdx.x*256 + threadIdx.x; if (i < n) p[i] = 0.f; }

__global__ __launch_bounds__(256) void fillv(float* __restrict__ p, int n, float v)
{ const int i = blockIdx.x*256 + threadIdx.x; if (i < n) p[i] = v; }

// ---------- ball query, wave-parallel; FEATb[z][k*NPTS+m][8] bf16 ----------
__global__ __launch_bounds__(256) void bq_feat(const float* __restrict__ src,
                                               const float* __restrict__ tgt,
                                               short* __restrict__ featb)
{
  const int z = blockIdx.y;
  const float* xyz = (z < 2) ? src + (size_t)z*NPTS*3 : tgt + (size_t)(z-2)*NPTS*3;
  __shared__ float cs[NPTS*3];
  for (int i = threadIdx.x; i < NPTS*3; i += 256) cs[i] = xyz[i];
  __syncthreads();
  const int wave = threadIdx.x >> 6, lane = threadIdx.x & 63;
  const int m = blockIdx.x*4 + wave;
  short* fb = featb + (long long)z*SPC*8;
  const float px = cs[3*m], py = cs[3*m+1], pz = cs[3*m+2];
  const float sqm = __fadd_rn(__fadd_rn(__fmul_rn(px,px), __fmul_rn(py,py)), __fmul_rn(pz,pz));
  const short pxh = f2b(px), pyh = f2b(py), pzh = f2b(pz);
  int cnt = 0;
  float frx = 0.f, fry = 0.f, frz = 0.f;
  for (int r = 0; r < 32; ++r) {
    const int n = r*64 + lane;
    const float xn = cs[3*n], yn = cs[3*n+1], zn = cs[3*n+2];
    const float sqn = __fadd_rn(__fadd_rn(__fmul_rn(xn,xn), __fmul_rn(yn,yn)), __fmul_rn(zn,zn));
    const float dt  = __fadd_rn(__fadd_rn(__fmul_rn(px,xn), __fmul_rn(py,yn)), __fmul_rn(pz,zn));
    const float d   = __fsub_rn(__fadd_rn(sqm, sqn), __fmul_rn(2.0f, dt));
    const bool hit = (d <= 0.09f);
    const unsigned long long mask = __ballot(hit);
    const int pre = __popcll(mask & ((1ull << lane) - 1ull));
    const int slot = cnt + pre;
    const float rx = xn-px, ry = yn-py, rz = zn-pz;
    if (hit && slot < KNB) {
      short tmp[8] = {pxh, pyh, pzh, f2b(rx), f2b(ry), f2b(rz), 0, 0};
      uint4 raw; __builtin_memcpy(&raw, tmp, 16);
      *(uint4*)&fb[((long long)slot*NPTS + m)*8] = raw;
    }
    if (cnt == 0 && mask) {
      const int fl = __ffsll(mask) - 1;
      frx = __shfl(rx, fl); fry = __shfl(ry, fl); frz = __shfl(rz, fl);
    }
    cnt += __popcll(mask);
    if (cnt >= KNB) break;
  }
  if (cnt < KNB && lane < KNB - cnt) {
    const int slot = cnt + lane;
    short tmp[8] = {pxh, pyh, pzh, f2b(frx), f2b(fry), f2b(frz), 0, 0};
    uint4 raw; __builtin_memcpy(&raw, tmp, 16);
    *(uint4*)&fb[((long long)slot*NPTS + m)*8] = raw;
  }
}

// ---------- universal MFMA GEMM ----------
// out[z][s][o] = sum_k f(A[z][s][k]) * Bw[z][o][k]  (+bias[o]) (*rowScale[z][s])
//   ABF16: A bf16; f = GN(stats)+relu if inStats.  !ABF16: A fp32; f = (A - A2) if A2.
// out fp32 or bf16 [S][N]; optional {sum,sumsq} atomics per o-group of grpCh.
// block 256 = 4 waves; tile 128(s) x 64(o); K mult of 8.
template<int ABF16>
__global__ __launch_bounds__(256) void mm(
    const void* __restrict__ Ap, long long ldA, long long aZ,
    const float* __restrict__ A2, long long ldA2, long long a2Z,
    const short* __restrict__ Bw, long long bZ,
    void* __restrict__ outp, long long ldo, long long oZ, int outBf16,
    const float* __restrict__ bias,
    const float* __restrict__ rowScale, long long rsZ,
    const float* __restrict__ inStats, long long isZ,
    const float* __restrict__ inW, const float* __restrict__ inB,
    float* __restrict__ outPart, long long pZ, int grpCh,
    int N, int K, int S)
{
  constexpr int RP = 40;
  __shared__ __align__(16) short As[128*RP];
  __shared__ __align__(16) short Bs[64*RP];
  __shared__ float rowS[64], rowQ[64], gSs[4], gQs[4];
  const int tid = threadIdx.x;
  const int z = blockIdx.z;
  const int s_blk = blockIdx.x*128;
  const int o_blk = blockIdx.y*64;
  const int lane = tid & 63;
  const int widx = tid >> 6;
  const int w_s = widx & 1, w_o = widx >> 1;
  const int l15 = lane & 15, l4 = lane >> 4;

  const short* Bz = Bw + (long long)z*bZ;
  const float* stz = inStats ? inStats + (long long)z*isZ : nullptr;

  f32x4 acc[2][4];
  #pragma unroll
  for (int i = 0; i < 2; ++i)
    #pragma unroll
    for (int j = 0; j < 4; ++j) acc[i][j] = (f32x4){0.f,0.f,0.f,0.f};

  if (outPart) {
    if (tid < 64) { rowS[tid] = 0.f; rowQ[tid] = 0.f; }
    if (tid < 4)  { gSs[tid] = 0.f; gQs[tid] = 0.f; }
  }

  for (int c0 = 0; c0 < K; c0 += 32) {
    __syncthreads();
    #pragma unroll
    for (int it = 0; it < 2; ++it) {
      const int ch = tid + it*256;
      const int row = ch >> 2, cq = ch & 3;
      const int gc = c0 + cq*8;
      uint4 raw = make_uint4(0,0,0,0);
      if (gc < K) {
        const long long base = (long long)(s_blk+row)*ldA + gc;
        if (ABF16) {
          raw = *(const uint4*)((const short*)Ap + (long long)z*aZ + base);
          if (stz) {
            short vs[8]; __builtin_memcpy(vs, &raw, 16);
            const int g = gc >> 5;
            const float mu = stz[2*g], rsg = stz[2*g+1];
            short tmp[8];
            #pragma unroll
            for (int j = 0; j < 8; ++j) {
              const float v = (b2f(vs[j]) - mu)*rsg*inW[gc+j] + inB[gc+j];
              tmp[j] = f2b(fmaxf(v, 0.f));
            }
            __builtin_memcpy(&raw, tmp, 16);
          }
        } else {
          const float* Af = (const float*)Ap + (long long)z*aZ + base;
          float4 u0 = *(const float4*)Af;
          float4 u1 = *(const float4*)(Af + 4);
          if (A2) {
            const float* Sf = A2 + (long long)z*a2Z + (long long)(s_blk+row)*ldA2 + gc;
            const float4 s0 = *(const float4*)Sf, s1 = *(const float4*)(Sf + 4);
            u0.x -= s0.x; u0.y -= s0.y; u0.z -= s0.z; u0.w -= s0.w;
            u1.x -= s1.x; u1.y -= s1.y; u1.z -= s1.z; u1.w -= s1.w;
          }
          short tmp[8] = {f2b(u0.x),f2b(u0.y),f2b(u0.z),f2b(u0.w),
                          f2b(u1.x),f2b(u1.y),f2b(u1.z),f2b(u1.w)};
          __builtin_memcpy(&raw, tmp, 16);
        }
      }
      *(uint4*)&As[row*RP + cq*8] = raw;
    }
    {
      const int row = tid >> 2, cq = tid & 3;
      const int gc = c0 + cq*8, go = o_blk + row;
      uint4 raw = make_uint4(0,0,0,0);
      if (go < N && gc < K)
        raw = *(const uint4*)(Bz + (long long)go*K + gc);
      *(uint4*)&Bs[row*RP + cq*8] = raw;
    }
    __syncthreads();
    bf16x8 af[4], bfr[2];
    #pragma unroll
    for (int ts = 0; ts < 4; ++ts)
      af[ts] = *(const bf16x8*)&As[(w_s*64 + ts*16 + l15)*RP + l4*8];
    #pragma unroll
    for (int to = 0; to < 2; ++to)
      bfr[to] = *(const bf16x8*)&Bs[(w_o*32 + to*16 + l15)*RP + l4*8];
    #pragma unroll
    for (int to = 0; to < 2; ++to)
      #pragma unroll
      for (int ts = 0; ts < 4; ++ts)
        acc[to][ts] = __builtin_amdgcn_mfma_f32_16x16x32_bf16(af[ts], bfr[to], acc[to][ts], 0, 0, 0);
  }

  const int s_base = s_blk + w_s*64;
  const int o_base = o_blk + w_o*32;
  float* ozF = (float*)outp + (long long)z*oZ;
  short* ozH = (short*)outp + (long long)z*oZ;
  #pragma unroll
  for (int to = 0; to < 2; ++to) {
    const int o = o_base + to*16 + l15;
    const bool ov = (o < N);
    const float bv = (bias && ov) ? bias[o] : 0.f;
    float ps = 0.f, pq = 0.f;
    #pragma unroll
    for (int ts = 0; ts < 4; ++ts) {
      #pragma unroll
      for (int r = 0; r < 4; ++r) {
        const int s = s_base + ts*16 + l4*4 + r;
        float v = acc[to][ts][r] + bv;
        if (rowScale) v *= rowScale[(long long)z*rsZ + s];
        if (ov) {
          if (outBf16) ozH[(long long)s*ldo + o] = f2b(v);
          else         ozF[(long long)s*ldo + o] = v;
          ps += v; pq = fmaf(v, v, pq);
        }
      }
    }
    if (outPart) {
      ps += __shfl_down(ps, 32); pq += __shfl_down(pq, 32);
      ps += __shfl_down(ps, 16); pq += __shfl_down(pq, 16);
      if (lane < 16) {
        atomicAdd(&rowS[w_o*32 + to*16 + l15], ps);
        atomicAdd(&rowQ[w_o*32 + to*16 + l15], pq);
      }
    }
  }
  if (outPart) {
    __syncthreads();
    if (tid < 64) {
      const int o = o_blk + tid;
      if (o < N) {
        const int gl = o/grpCh - o_blk/grpCh;
        atomicAdd(&gSs[gl], rowS[tid]);
        atomicAdd(&gQs[gl], rowQ[tid]);
      }
    }
    __syncthreads();
    const int g0 = o_blk/grpCh;
    const int hi = (o_blk + 63 < N - 1) ? o_blk + 63 : N - 1;
    if (tid <= hi/grpCh - g0) {
      float* pp = outPart + (long long)z*pZ;
      atomicAdd(&pp[2*(g0+tid)],   gSs[tid]);
      atomicAdd(&pp[2*(g0+tid)+1], gQs[tid]);
    }
  }
}

// ---------- finalize GN stats ----------
__global__ void fin_stats(float* __restrict__ part, float* __restrict__ stats,
                          long long slotStride, int G, float invGS)
{
  const int g = threadIdx.x;
  float* p  = part  + (long long)blockIdx.x * slotStride;
  float* st = stats + (long long)blockIdx.x * slotStride;
  if (g < G) {
    const float mu  = p[2*g] * invGS;
    const float var = p[2*g+1] * invGS - mu*mu;
    st[2*g]   = mu;
    st[2*g+1] = rsqrtf(var + 1e-5f);
    p[2*g] = 0.f; p[2*g+1] = 0.f;
  }
}

// ---------- maxpool accumulate: C3t[z][r*NPTS+n][192] bf16 -> POOLt[z][n][192] ----------
__global__ __launch_bounds__(192) void maxpool_racc(const short* __restrict__ c3t, int kc,
                                                    long long c3Z, float* __restrict__ pool)
{
  const int n = blockIdx.x, z = blockIdx.y, c = threadIdx.x;
  const short* b = c3t + (long long)z*c3Z;
  float m = -1e30f;
  for (int r = 0; r < kc; ++r)
    m = fmaxf(m, b2f(b[((long long)r*NPTS + n)*192 + c]));
  float* p = &pool[((long long)z*NPTS + n)*192 + c];
  *p = fmaxf(*p, m);
}

// ---------- gn+relu on POOLt [4][NPTS][192] ----------
__global__ __launch_bounds__(256) void gn_pool(float* __restrict__ pool,
    const float* __restrict__ stats, const float* __restrict__ w, const float* __restrict__ b)
{
  const int i = blockIdx.x*256 + threadIdx.x;
  const int z = i / (NPTS*192);
  const int c = i % 192;
  const int g = c >> 5;
  const float* st = stats + z*64;
  const float v = (pool[i] - st[2*g]) * st[2*g+1] * w[c] + b[c];
  pool[i] = fmaxf(v, 0.f);
}

// ---------- FEATS slot[n][c] = xin[n][c] + relu(gn(t[n][c])) ----------
__global__ __launch_bounds__(256) void gn_resid(const float* __restrict__ t,
    const float* __restrict__ xin, long long xZ, long long xld,
    const float* __restrict__ stats,
    const float* __restrict__ w, const float* __restrict__ b,
    float* __restrict__ outp, long long oZ)
{
  const int i = blockIdx.x*256 + threadIdx.x;
  const int z = blockIdx.y;
  const int n = i / 192, c = i % 192, g = c >> 5;
  const float* st = stats + z*16;
  const float v = (t[(long long)z*NPTS*192 + i] - st[2*g]) * st[2*g+1] * w[c] + b[c];
  outp[(long long)z*oZ + (long long)n*768 + c] =
      xin[(long long)z*xZ + (long long)n*xld + c] + fmaxf(v, 0.f);
}

// ---------- row softmax on ATT fp32 [z][n][m] ----------
__global__ __launch_bounds__(256) void softmax_rows(float* __restrict__ att)
{
  float* a = att + ((long long)blockIdx.y*NPTS + blockIdx.x)*NPTS;
  const int tid = threadIdx.x;
  __shared__ float red[256];
  float mx = -1e30f;
  for (int m = tid; m < NPTS; m += 256) mx = fmaxf(mx, a[m]);
  red[tid] = mx; __syncthreads();
  for (int st = 128; st; st >>= 1) { if (tid < st) red[tid] = fmaxf(red[tid], red[tid+st]); __syncthreads(); }
  mx = red[0]; __syncthreads();
  float sum = 0.f;
  for (int m = tid; m < NPTS; m += 256) { const float e = expf(a[m] - mx); a[m] = e; sum += e; }
  red[tid] = sum; __syncthreads();
  for (int st = 128; st; st >>= 1) { if (tid < st) red[tid] += red[tid+st]; __syncthreads(); }
  const float inv = 1.0f / red[0];
  for (int m = tid; m < NPTS; m += 256) a[m] *= inv;
}

// ---------- transpose -> bf16: src[z][R][C] -> dst[z][C][R] ----------
template<int SRCF32>
__global__ __launch_bounds__(256) void tr2bf(const void* __restrict__ src, short* __restrict__ dst,
                                             long long sZ, long long dZ, int R, int C)
{
  __shared__ float t[32][33];
  const int z = blockIdx.z;
  const int c0 = blockIdx.x*32, r0 = blockIdx.y*32;
  const int tx = threadIdx.x % 32, ty = threadIdx.x / 32;
  #pragma unroll
  for (int j = 0; j < 4; ++j) {
    const int r = r0 + ty + j*8;
    const long long idx = (long long)z*sZ + (long long)r*C + c0 + tx;
    t[ty + j*8][tx] = SRCF32 ? ((const float*)src)[idx] : b2f(((const short*)src)[idx]);
  }
  __syncthreads();
  #pragma unroll
  for (int j = 0; j < 4; ++j) {
    const int c = c0 + ty + j*8;
    dst[(long long)z*dZ + (long long)c*R + r0 + tx] = f2b(t[tx][ty + j*8]);
  }
}

// ---------- per-row sums of ATTB [z][m][n] -> SINV[z][m] = 1/(1e-9+sum) ----------
__global__ __launch_bounds__(256) void colsum_rows(const short* __restrict__ attb,
                                                   float* __restrict__ sinv)
{
  const int wave = threadIdx.x >> 6, lane = threadIdx.x & 63;
  const int m = blockIdx.x*4 + wave, z = blockIdx.y;
  const short* row = attb + (long long)z*NPTS*NPTS + (long long)m*NPTS;
  float s = 0.f;
  for (int j = 0; j < NPTS/64; ++j) s += b2f(row[lane + j*64]);
  s += __shfl_down(s, 32); s += __shfl_down(s, 16);
  s += __shfl_down(s, 8);  s += __shfl_down(s, 4);
  s += __shfl_down(s, 2);  s += __shfl_down(s, 1);
  if (lane == 0) sinv[z*NPTS + m] = 1.0f / (1e-9f + s);
}

// ---------- fuse epilogue: GN(16x48) + leaky(0.2) + L2 norm ----------
__global__ __launch_bounds__(256) void finalize_gn(const float* __restrict__ fused,
    const float* __restrict__ stats, const float* __restrict__ w, const float* __restrict__ b,
    float* __restrict__ outp, long long oZ)
{
  const int n = blockIdx.x, z = blockIdx.y, tid = threadIdx.x;
  const float* fz = fused + ((long long)z*NPTS + n)*768;
  const float* st = stats + z*32;
  __shared__ float vbuf[768];
  __shared__ float red[256];
  float ss = 0.f;
  for (int c = tid; c < 768; c += 256) {
    float v = fz[c];
    const int g = c / 48;
    v = (v - st[2*g]) * st[2*g+1] * w[c] + b[c];
    v = v > 0.f ? v : 0.2f * v;
    vbuf[c] = v;
    ss = fmaf(v, v, ss);
  }
  red[tid] = ss; __syncthreads();
  for (int st_ = 128; st_; st_ >>= 1) { if (tid < st_) red[tid] += red[tid+st_]; __syncthreads(); }
  const float inv = 1.0f / (sqrtf(red[0]) + 1e-8f);
  float* ob = outp + (long long)z*oZ + (long long)n*768;
  for (int c = tid; c < 768; c += 256) ob[c] = vbuf[c] * inv;
}

extern "C" void kernel_launch(void* const* d_in, const int* in_sizes, int n_in,
                              void* d_out, int out_size, void* d_ws, size_t ws_size,
                              hipStream_t stream)
{
  const float* src = (const float*)d_in[0];
  const float* tgt = (const float*)d_in[1];
  const float* lfw[3]  = {(const float*)d_in[5], (const float*)d_in[8],  (const float*)d_in[11]};
  const float* lfgw[3] = {(const float*)d_in[6], (const float*)d_in[9],  (const float*)d_in[12]};
  const float* lfgb[3] = {(const float*)d_in[7], (const float*)d_in[10], (const float*)d_in[13]};
  const float* qk_w = (const float*)d_in[14];
  const float* v_w  = (const float*)d_in[15];
  const float* v_b  = (const float*)d_in[16];
  const float* t_w  = (const float*)d_in[17];
  const float* t_b  = (const float*)d_in[18];
  const float* bgw  = (const float*)d_in[19];
  const float* bgb  = (const float*)d_in[20];
  const float* fw   = (const float*)d_in[21];
  const float* fgw  = (const float*)d_in[22];
  const float* fgb  = (const float*)d_in[23];
  float* dout = (float*)d_out;

  const size_t availFl = ws_size / sizeof(float);
  float* ws = (float*)d_ws;
  size_t off = 0;
  float* POOLt = ws + off; off += (size_t)4*NPTS*192;     // [4][n][192]
  float* PART  = ws + off; off += 1024;
  float* STATS = ws + off; off += 1024;
  float* SINV  = ws + off; off += (size_t)4*NPTS;
  // bf16 weights
  short* wreg = (short*)(ws + off);
  short* lfw0b = wreg;              // 128x8
  short* lfw1b = lfw0b + 1024;      // 256x128
  short* lfw2b = lfw1b + 32768;     // 192x256
  short* qkwb  = lfw2b + 49152;     // 4x48x192
  short* vwb   = qkwb + 36864;      // 4x192x192
  short* twb   = vwb + 147456;      // 4x192x192
  short* fwb   = twb + 147456;      // 768x768
  off += (1024+32768+49152+36864+147456+147456+589824 + 1)/2 + 8;
  short* FEATb = (short*)(ws + off); off += (size_t)4*SPC*8/2;  // [4][k*NPTS+m][8]
  off = (off + 63) & ~(size_t)63;
  float* REG = ws + off;
  const size_t regAvail = (availFl > off) ? (availFl - off) : 0;

  // attention batching
  const size_t perZ = 9093120;   // floats per z (see carve below)
  int nz;
  if      (regAvail >= 4*perZ) nz = 4;
  else if (regAvail >= 2*perZ) nz = 2;
  else if (regAvail >= perZ)   nz = 1;
  else return;
  // conv chunking (z=4 batched): floats = 2,359,296 * kc
  int kc = 0;
  for (int cand = 64; cand >= 1; cand >>= 1)
    if ((size_t)2359296*cand <= regAvail) { kc = cand; break; }
  if (!kc) return;
  const int Sc = kc * NPTS;
  const int nChunks = KNB / kc;

  // conv view of REG
  short* C1t = (short*)REG;                         // [4][Sc][128]
  short* C2t = C1t + (size_t)4*Sc*128;              // [4][Sc][256]
  short* C3t = C2t + (size_t)4*Sc*256;              // [4][Sc][192]
  // attn view of REG
  float* ATT   = REG;                               // [nz][n][m]
  float* XRt   = ATT + (size_t)nz*NPTS*NPTS;        // [nz][n][192]
  float* Tt    = XRt + (size_t)nz*NPTS*192;         // [nz][n][192]
  float* FUSED = Tt  + (size_t)nz*NPTS*192;         // [nz][n][768]
  short* QKT   = (short*)(FUSED + (size_t)nz*NPTS*768);  // [nz][n][48]
  short* Vt    = QKT + (size_t)nz*NPTS*48;          // [nz][n][192]
  short* Vc    = Vt  + (size_t)nz*NPTS*192;         // [nz][192][n]
  short* ATTB  = Vc  + (size_t)nz*NPTS*192;         // [nz][m][n]

  dim3 b256(256);
  const float invConv = 1.0f / (32.0f * (float)SPC);

  // weight conversion + zero PART
  cvt_w<<<dim3(4),   b256, 0, stream>>>(lfw[0], lfw0b, 128, 6, 8);
  cvt_w<<<dim3(128), b256, 0, stream>>>(lfw[1], lfw1b, 256, 128, 128);
  cvt_w<<<dim3(192), b256, 0, stream>>>(lfw[2], lfw2b, 192, 256, 256);
  cvt_w<<<dim3(144), b256, 0, stream>>>(qk_w, qkwb, 192, 192, 192);
  cvt_w<<<dim3(576), b256, 0, stream>>>(v_w,  vwb,  768, 192, 192);
  cvt_w<<<dim3(576), b256, 0, stream>>>(t_w,  twb,  768, 192, 192);
  cvt_w<<<dim3(2304),b256, 0, stream>>>(fw,   fwb,  768, 768, 768);
  fill0<<<dim3(4), b256, 0, stream>>>(PART, 1024);

  // ---- ball query (all 4 clouds) ----
  bq_feat<<<dim3(NPTS/4, 4), b256, 0, stream>>>(src, tgt, FEATb);

  // ---- conv stage, z=4 batched, chunked with recompute if needed ----
  // pass 1: conv1 -> stats1
  for (int ck = 0; ck < nChunks; ++ck)
    mm<1><<<dim3(Sc/128, 2, 4), b256, 0, stream>>>(
        FEATb + (size_t)ck*Sc*8, 8, (long long)SPC*8, nullptr,0,0,
        lfw0b, 0, C1t, 128, (long long)Sc*128, 1,
        nullptr, nullptr,0, nullptr,0,nullptr,nullptr,
        PART, 64, 32, 128, 8, Sc);
  fin_stats<<<4, 32, 0, stream>>>(PART, STATS, 64, 4, invConv);
  // pass 2: (conv1) -> conv2 -> stats2
  for (int ck = 0; ck < nChunks; ++ck) {
    if (nChunks > 1)
      mm<1><<<dim3(Sc/128, 2, 4), b256, 0, stream>>>(
          FEATb + (size_t)ck*Sc*8, 8, (long long)SPC*8, nullptr,0,0,
          lfw0b, 0, C1t, 128, (long long)Sc*128, 1,
          nullptr, nullptr,0, nullptr,0,nullptr,nullptr,
          nullptr, 0, 1, 128, 8, Sc);
    mm<1><<<dim3(Sc/128, 4, 4), b256, 0, stream>>>(
        C1t, 128, (long long)Sc*128, nullptr,0,0,
        lfw1b, 0, C2t, 256, (long long)Sc*256, 1,
        nullptr, nullptr,0, STATS,64, lfgw[0], lfgb[0],
        PART+256, 64, 32, 256, 128, Sc);
  }
  fin_stats<<<4, 32, 0, stream>>>(PART+256, STATS+256, 64, 8, invConv);
  // pass 3: (conv1 -> conv2) -> conv3 -> stats3 + maxpool
  fillv<<<dim3(4*NPTS*192/256), b256, 0, stream>>>(POOLt, 4*NPTS*192, -1e30f);
  for (int ck = 0; ck < nChunks; ++ck) {
    if (nChunks > 1) {
      mm<1><<<dim3(Sc/128, 2, 4), b256, 0, stream>>>(
          FEATb + (size_t)ck*Sc*8, 8, (long long)SPC*8, nullptr,0,0,
          lfw0b, 0, C1t, 128, (long long)Sc*128, 1,
          nullptr, nullptr,0, nullptr,0,nullptr,nullptr,
          nullptr, 0, 1, 128, 8, Sc);
      mm<1><<<dim3(Sc/128, 4, 4), b256, 0, stream>>>(
          C1t, 128, (long long)Sc*128, nullptr,0,0,
          lfw1b, 0, C2t, 256, (long long)Sc*256, 1,
          nullptr, nullptr,0, STATS,64, lfgw[0], lfgb[0],
          nullptr, 0, 1, 256, 128, Sc);
    }
    mm<1><<<dim3(Sc/128, 3, 4), b256, 0, stream>>>(
        C2t, 256, (long long)Sc*256, nullptr,0,0,
        lfw2b, 0, C3t, 192, (long long)Sc*192, 1,
        nullptr, nullptr,0, STATS+256,64, lfgw[1], lfgb[1],
        PART+512, 64, 32, 192, 256, Sc);
    maxpool_racc<<<dim3(NPTS, 4), dim3(192), 0, stream>>>(C3t, kc, (long long)Sc*192, POOLt);
  }
  fin_stats<<<4, 32, 0, stream>>>(PART+512, STATS+512, 64, 6, invConv);
  gn_pool<<<dim3(4*NPTS*192/256), b256, 0, stream>>>(POOLt, STATS+512, lfgw[2], lfgb[2]);

  // ---- attention + fuse, nz clouds per batch ----
  for (int bb0 = 0; bb0 < 4; bb0 += nz) {
    for (int i = 0; i < 4; ++i) {
      const float* Xin; long long xZ, xld;
      if (i == 0) { Xin = POOLt + (size_t)bb0*NPTS*192; xZ = (long long)NPTS*192; xld = 192; }
      else        { Xin = dout + (size_t)bb0*NPTS*768 + (size_t)(i-1)*192; xZ = (long long)NPTS*768; xld = 768; }
      // qk -> QKT [n][48] bf16
      mm<0><<<dim3(16, 1, nz), b256, 0, stream>>>(
          Xin, xld, xZ, nullptr,0,0,
          qkwb + (size_t)i*48*192, 0, QKT, 48, (long long)NPTS*48, 1,
          nullptr, nullptr,0, nullptr,0,nullptr,nullptr,
          nullptr, 0, 1, 48, 192, NPTS);
      // v -> Vt [n][192] bf16 (+bias)
      mm<0><<<dim3(16, 3, nz), b256, 0, stream>>>(
          Xin, xld, xZ, nullptr,0,0,
          vwb + (size_t)i*192*192, 0, Vt, 192, (long long)NPTS*192, 1,
          v_b + (size_t)i*192, nullptr,0, nullptr,0,nullptr,nullptr,
          nullptr, 0, 1, 192, 192, NPTS);
      // att[n][m] = QKT . QKT^T -> fp32
      mm<1><<<dim3(16, 32, nz), b256, 0, stream>>>(
          QKT, 48, (long long)NPTS*48, nullptr,0,0,
          QKT, (long long)NPTS*48, ATT, NPTS, (long long)NPTS*NPTS, 0,
          nullptr, nullptr,0, nullptr,0,nullptr,nullptr,
          nullptr, 0, 1, NPTS, 48, NPTS);
      softmax_rows<<<dim3(NPTS, nz), b256, 0, stream>>>(ATT);
      tr2bf<1><<<dim3(64, 64, nz), b256, 0, stream>>>(ATT, ATTB,
          (long long)NPTS*NPTS, (long long)NPTS*NPTS, NPTS, NPTS);
      colsum_rows<<<dim3(NPTS/4, nz), b256, 0, stream>>>(ATTB, SINV);
      tr2bf<0><<<dim3(6, 64, nz), b256, 0, stream>>>(Vt, Vc,
          (long long)NPTS*192, (long long)192*NPTS, NPTS, 192);
      // x_r^T [m][192] = (ATTB . Vc^T) * sinv[m]
      mm<1><<<dim3(16, 3, nz), b256, 0, stream>>>(
          ATTB, NPTS, (long long)NPTS*NPTS, nullptr,0,0,
          Vc, (long long)192*NPTS, XRt, 192, (long long)NPTS*192, 0,
          nullptr, SINV, NPTS, nullptr,0,nullptr,nullptr,
          nullptr, 0, 1, 192, NPTS, NPTS);
      // t [n][192] = (x - x_r) . t_w^T + t_b, + stats
      mm<0><<<dim3(16, 3, nz), b256, 0, stream>>>(
          Xin, xld, xZ, XRt, 192, (long long)NPTS*192,
          twb + (size_t)i*192*192, 0, Tt, 192, (long long)NPTS*192, 0,
          t_b + (size_t)i*192, nullptr,0, nullptr,0,nullptr,nullptr,
          PART+768, 16, 32, 192, 192, NPTS);
      fin_stats<<<nz, 32, 0, stream>>>(PART+768, STATS+768, 16, 6, 1.0f/65536.0f);
      gn_resid<<<dim3(NPTS*192/256, nz), b256, 0, stream>>>(
          Tt, Xin, xZ, xld, STATS+768,
          bgw + (size_t)i*192, bgb + (size_t)i*192,
          dout + (size_t)bb0*NPTS*768 + (size_t)i*192, (long long)NPTS*768);
    }
    // fuse: FEATS [n][768] (fp32, in d_out) . fwb^T -> FUSED fp32 + stats
    mm<0><<<dim3(16, 12, nz), b256, 0, stream>>>(
        dout + (size_t)bb0*NPTS*768, 768, (long long)NPTS*768, nullptr,0,0,
        fwb, 0, FUSED, 768, (long long)NPTS*768, 0,
        nullptr, nullptr,0, nullptr,0,nullptr,nullptr,
        PART+832, 32, 48, 768, 768, NPTS);
    fin_stats<<<nz, 32, 0, stream>>>(PART+832, STATS+832, 32, 16, 1.0f/98304.0f);
    finalize_gn<<<dim3(NPTS, nz), b256, 0, stream>>>(
        FUSED, STATS+832, fgw, fgb,
        dout + (size_t)bb0*NPTS*768, (long long)NPTS*768);
  }
}